// Round 6
// baseline (115.476 us; speedup 1.0000x reference)
//
#include <hip/hip_runtime.h>

// Problem constants (reference: B=32, L=64, C=4)
#define BB 32
#define LL 64
#define LC 256
#define NPAIR 2016
#define PPB 4            // pairs per block
#define NBLK (NPAIR / PPB)  // 504 blocks

// Single fused kernel. 504 blocks x 256 threads (32 b x 8 k), 4 pairs/block.
// Per-thread one-hot codes live in registers (computed once from L1-resident
// x). Theta3 inner loop: dense float4 reads of the row tail (affine address,
// no load in the address path) + register component select. One atomicAdd
// per (b, block) at the end. Block 0 also folds in theta1 (codes already in
// registers) and theta0.
__global__ __launch_bounds__(256) void fused_kernel(
    const float* __restrict__ x, const float* __restrict__ t0,
    const float* __restrict__ t1, const float* __restrict__ t2,
    const float* __restrict__ t3, float* __restrict__ out)
{
    const int g = blockIdx.x;
    const int tid = threadIdx.x;
    const int b = tid >> 3, k = tid & 7;
    const float4* __restrict__ x4 = (const float4*)x + b * 64;

    // my 8 codes: c[m] = argmax_c x[b, 8m+k, c]
    int c[8];
#pragma unroll
    for (int m = 0; m < 8; ++m) {
        float4 f = x4[8 * m + k];
        int ci = 0; float best = f.x;
        if (f.y > best) { best = f.y; ci = 1; }
        if (f.z > best) { best = f.z; ci = 2; }
        if (f.w > best) { best = f.w; ci = 3; }
        c[m] = ci;
    }

    // decode first pair t = g*4 into (u,v), then step through 4 pairs
    int t = g * PPB;
    int v = (int)((1.0f + sqrtf(8.0f * (float)t + 1.0f)) * 0.5f);
    while (v * (v - 1) / 2 > t) --v;
    while ((v + 1) * v / 2 <= t) ++v;
    int u = t - v * (v - 1) / 2;

    float acc = 0.0f;
#pragma unroll
    for (int p = 0; p < PPB; ++p) {
        // codes at u and v (L1-hit broadcast loads)
        float4 fu = x4[u], fv = x4[v];
        int cu = 0; { float bst = fu.x;
            if (fu.y > bst) { bst = fu.y; cu = 1; }
            if (fu.z > bst) { bst = fu.z; cu = 2; }
            if (fu.w > bst) { bst = fu.w; cu = 3; } }
        int cv = 0; { float bst = fv.x;
            if (fv.y > bst) { bst = fv.y; cv = 1; }
            if (fv.z > bst) { bst = fv.z; cv = 2; }
            if (fv.w > bst) { bst = fv.w; cv = 3; } }
        const int pu = 4 * u + cu, pv = 4 * v + cv;

        const float4* __restrict__ row4 =
            (const float4*)(t3 + ((size_t)pu << 16) + ((size_t)pv << 8));
        const int mstart = (v + 1 - k + 7) >> 3;  // first m with 8m+k >= v+1
#pragma unroll
        for (int m = 0; m < 8; ++m) {
            if (m >= mstart) {
                float4 f = row4[8 * m + k];       // dense, affine address
                float s0 = (c[m] & 2) ? f.z : f.x;
                float s1 = (c[m] & 2) ? f.w : f.y;
                acc += (c[m] & 1) ? s1 : s0;
            }
        }
        if (k == 0) acc += t2[pu * LC + pv];

        // next pair in triangular order
        ++u; if (u == v) { u = 0; ++v; }
    }

    // order-1: block 0's threads cover all (b, w=8m+k) exactly once
    if (g == 0) {
#pragma unroll
        for (int m = 0; m < 8; ++m)
            acc += t1[4 * (8 * m + k) + c[m]];
    }

    // width-8 shuffle reduce over k, then one atomic per (b, block)
    acc += __shfl_down(acc, 4, 8);
    acc += __shfl_down(acc, 2, 8);
    acc += __shfl_down(acc, 1, 8);
    if (k == 0) {
        if (g == 0) acc += t0[0];
        atomicAdd(&out[b], acc);
    }
}

extern "C" void kernel_launch(void* const* d_in, const int* in_sizes, int n_in,
                              void* d_out, int out_size, void* d_ws, size_t ws_size,
                              hipStream_t stream) {
    const float* x  = (const float*)d_in[0];  // (B, L*C)
    const float* t0 = (const float*)d_in[1];  // (1,)
    const float* t1 = (const float*)d_in[2];  // (L, C)
    const float* t2 = (const float*)d_in[3];  // (L, C, L, C)
    const float* t3 = (const float*)d_in[4];  // (L, C, L, C, L, C)
    float* out = (float*)d_out;               // (B, 1)

    hipMemsetAsync(out, 0, BB * sizeof(float), stream);
    fused_kernel<<<NBLK, 256, 0, stream>>>(x, t0, t1, t2, t3, out);
}

// Round 7
// 104.515 us; speedup vs baseline: 1.1049x; 1.1049x over previous
//
#include <hip/hip_runtime.h>

// Problem constants (reference: B=32, L=64, C=4)
#define BB 32
#define LL 64
#define LC 256
#define NPAIR 2016
#define WSTRIDE 2048   // ws2[b][t] padded stride (floats)

// One block per pair t=(u,v), u<v. 256 threads = 32 b * 8 k.
// Codes recomputed from L1-resident x in registers (no cross-kernel control
// data, no LDS, no barrier). Theta3 loads: scalar dwords at row[4w + c[m]]
// -- address is pure ALU (c[m] in a register), 8 independent loads in
// flight. Cross-b reuse: 32 b's hit <=16 distinct theta3 rows -> L1/L2 merge.
__global__ __launch_bounds__(256) void pair_kernel(
    const float* __restrict__ x, const float* __restrict__ t2,
    const float* __restrict__ t3, float* __restrict__ ws2)
{
    const int t = blockIdx.x;
    // decode triangular index t = v*(v-1)/2 + u, 0 <= u < v < 64
    int v = (int)((1.0f + sqrtf(8.0f * (float)t + 1.0f)) * 0.5f);
    while (v * (v - 1) / 2 > t) --v;
    while ((v + 1) * v / 2 <= t) ++v;
    const int u = t - v * (v - 1) / 2;

    const int tid = threadIdx.x;
    const int b = tid >> 3, k = tid & 7;
    const float4* __restrict__ x4 = (const float4*)x + b * 64;

    float4 fu = x4[u], fv = x4[v];     // prefetch (L1 broadcast)

    // codes for my 8 w's (w = 8m + k), computed in registers
    int c[8];
#pragma unroll
    for (int m = 0; m < 8; ++m) {
        float4 f = x4[8 * m + k];
        int ci = 0; float best = f.x;
        if (f.y > best) { best = f.y; ci = 1; }
        if (f.z > best) { best = f.z; ci = 2; }
        if (f.w > best) { best = f.w; ci = 3; }
        c[m] = ci;
    }
    int cu = 0; { float bst = fu.x;
        if (fu.y > bst) { bst = fu.y; cu = 1; }
        if (fu.z > bst) { bst = fu.z; cu = 2; }
        if (fu.w > bst) { bst = fu.w; cu = 3; } }
    int cv = 0; { float bst = fv.x;
        if (fv.y > bst) { bst = fv.y; cv = 1; }
        if (fv.z > bst) { bst = fv.z; cv = 2; }
        if (fv.w > bst) { bst = fv.w; cv = 3; } }
    const int pu = 4 * u + cu, pv = 4 * v + cv;

    const float* __restrict__ row = t3 + ((size_t)pu << 16) + ((size_t)pv << 8);

    float acc = 0.0f;
    const int mstart = (v + 1 - k + 7) >> 3;   // first m with 8m+k >= v+1
#pragma unroll
    for (int m = 0; m < 8; ++m) {
        if (m >= mstart)
            acc += row[4 * (8 * m + k) + c[m]];  // scalar dword, ALU address
    }
    // width-8 shuffle reduce over k
    acc += __shfl_down(acc, 4, 8);
    acc += __shfl_down(acc, 2, 8);
    acc += __shfl_down(acc, 1, 8);
    if (k == 0) ws2[b * WSTRIDE + t] = acc + t2[pu * LC + pv];
}

// One block per b: sum 2016 partials (coalesced) + theta1 (argmax recomputed
// from x) + theta0.
__global__ __launch_bounds__(256) void reduce_kernel(
    const float* __restrict__ x, const float* __restrict__ t0,
    const float* __restrict__ t1, const float* __restrict__ ws2,
    float* __restrict__ out)
{
    const int b = blockIdx.x;
    const int tid = threadIdx.x;
    const float* __restrict__ wsb = ws2 + b * WSTRIDE;
    float v = 0.0f;
    for (int t = tid; t < NPAIR; t += 256) v += wsb[t];  // coalesced
    if (tid < LL) {
        float4 f = ((const float4*)x)[b * 64 + tid];
        int c = 0; float best = f.x;
        if (f.y > best) { best = f.y; c = 1; }
        if (f.z > best) { best = f.z; c = 2; }
        if (f.w > best) { best = f.w; c = 3; }
        v += t1[4 * tid + c];
    }
    for (int off = 32; off > 0; off >>= 1) v += __shfl_down(v, off, 64);
    __shared__ float wsum[4];
    if ((tid & 63) == 0) wsum[tid >> 6] = v;
    __syncthreads();
    if (tid == 0) out[b] = wsum[0] + wsum[1] + wsum[2] + wsum[3] + t0[0];
}

extern "C" void kernel_launch(void* const* d_in, const int* in_sizes, int n_in,
                              void* d_out, int out_size, void* d_ws, size_t ws_size,
                              hipStream_t stream) {
    const float* x  = (const float*)d_in[0];  // (B, L*C)
    const float* t0 = (const float*)d_in[1];  // (1,)
    const float* t1 = (const float*)d_in[2];  // (L, C)
    const float* t2 = (const float*)d_in[3];  // (L, C, L, C)
    const float* t3 = (const float*)d_in[4];  // (L, C, L, C, L, C)
    float* out = (float*)d_out;               // (B, 1)
    float* ws2 = (float*)d_ws;                // 32*2048 floats = 256 KB

    pair_kernel<<<NPAIR, 256, 0, stream>>>(x, t2, t3, ws2);
    reduce_kernel<<<BB, 256, 0, stream>>>(x, t0, t1, ws2, out);
}